// Round 1
// baseline (668.988 us; speedup 1.0000x reference)
//
#include <hip/hip_runtime.h>
#include <float.h>
#include <math.h>

#define NUM_GRAPHS 4096
#define EMB 128
#define CHUNK 32

// start[g] = first index i with batch[i] >= g (batch sorted ascending).
// g in [0, NUM_GRAPHS]; start[NUM_GRAPHS] = n.
__global__ void bounds_kernel(const int* __restrict__ batch, int n, int* __restrict__ start) {
    int g = blockIdx.x * blockDim.x + threadIdx.x;
    if (g > NUM_GRAPHS) return;
    int lo = 0, hi = n;
    while (lo < hi) {
        int mid = (lo + hi) >> 1;
        if (batch[mid] < g) lo = mid + 1; else hi = mid;
    }
    start[g] = lo;
}

// One block (256 threads) per graph. Single pass over this graph's rows of x:
// per 32-node chunk, fused (load -> LDS) + (score dot) via register w fragment,
// online-softmax state update, then weighted accumulation from LDS.
__global__ __launch_bounds__(256) void att_pool_kernel(
    const float* __restrict__ x, const float* __restrict__ w,
    const int* __restrict__ start, float* __restrict__ out)
{
    __shared__ float xs[CHUNK * EMB];   // 16 KB chunk tile (flat, matches global layout)
    __shared__ float s_lds[CHUNK];      // per-node scores
    __shared__ float p_lds[CHUNK];      // per-node exp(s - m)
    __shared__ float m_sh, l_sh, scale_sh;

    const int g = blockIdx.x;
    const int t = threadIdx.x;
    const int n0 = start[g];
    const int n1 = start[g + 1];
    const int cnt = n1 - n0;

    // Register-resident w fragment: thread t always loads global dims (4t)&127 .. +3,
    // independent of chunk/off — so one float4 of w covers all its score work.
    const int wd = (4 * t) & 127;
    const float4 w4 = *(const float4*)(w + wd);

    const int d   = t & 127;   // output dim this thread owns
    const int par = t >> 7;    // parity: which half of nodes this thread accumulates

    float acc = 0.f;           // running sum of exp(s_i - m) * x[i][d] over nodes i ≡ par (mod 2)

    if (t == 0) { m_sh = -FLT_MAX; l_sh = 0.f; }

    for (int i0 = n0; i0 < n1; i0 += CHUNK) {
        const int cc  = min(CHUNK, n1 - i0);
        const int lim = cc * EMB;
        const float* xg = x + (size_t)i0 * EMB;

        __syncthreads();  // xs/p_lds from previous iteration fully consumed; m/l init visible

        // ---- fused load + score: 256 threads x 4 float4 = 32x128 floats ----
        #pragma unroll
        for (int off = 0; off < 4; ++off) {
            const int flat = 4 * t + 1024 * off;   // float index within chunk
            float p = 0.f;
            if (flat < lim) {
                float4 v = *(const float4*)(xg + flat);
                *(float4*)(xs + flat) = v;
                p = v.x * w4.x + v.y * w4.y + v.z * w4.z + v.w * w4.w;
            }
            // 32 consecutive lanes hold partials of the same node -> shuffle reduce
            #pragma unroll
            for (int msk = 16; msk >= 1; msk >>= 1)
                p += __shfl_xor(p, msk, 32);
            if ((t & 31) == 0) {
                const int node = (t >> 5) + 8 * off;   // 0..31 across (t,off)
                s_lds[node] = p;
            }
        }
        __syncthreads();

        // ---- online softmax state update (wave 0, lanes 0..31) ----
        if (t < 32) {
            const float m_old = m_sh;
            float s = (t < cc) ? s_lds[t] : -FLT_MAX;
            float cmax = s;
            #pragma unroll
            for (int msk = 16; msk >= 1; msk >>= 1)
                cmax = fmaxf(cmax, __shfl_xor(cmax, msk, 32));
            const float m_new = fmaxf(m_old, cmax);
            const float pe = (t < cc) ? __expf(s - m_new) : 0.f;
            p_lds[t] = pe;
            float lsum = pe;
            #pragma unroll
            for (int msk = 16; msk >= 1; msk >>= 1)
                lsum += __shfl_xor(lsum, msk, 32);
            if (t == 0) {
                const float sc = __expf(m_old - m_new);  // underflows to 0 on first chunk
                scale_sh = sc;
                l_sh = l_sh * sc + lsum;
                m_sh = m_new;
            }
        }
        __syncthreads();

        // ---- weighted accumulation from LDS (2-way bank aliasing = free) ----
        acc *= scale_sh;
        for (int i = par; i < cc; i += 2)
            acc += p_lds[i] * xs[i * EMB + d];
    }

    // ---- epilogue: combine parity halves, normalize, store ----
    __syncthreads();
    if (par == 1) xs[d] = acc;
    __syncthreads();
    if (par == 0) {
        const float total = acc + xs[d];
        const float denom = fmaxf(l_sh, 1e-30f);
        const float cf    = (float)max(cnt, 1);
        out[(size_t)g * EMB + d] = total / (denom * cf);
    }
    // output 1: att_weight passthrough (one block writes it)
    if (g == 0 && t < EMB) {
        out[(size_t)NUM_GRAPHS * EMB + t] = w[t];
    }
}

extern "C" void kernel_launch(void* const* d_in, const int* in_sizes, int n_in,
                              void* d_out, int out_size, void* d_ws, size_t ws_size,
                              hipStream_t stream) {
    const float* x     = (const float*)d_in[0];
    const int*   batch = (const int*)d_in[1];
    const float* w     = (const float*)d_in[2];
    float* out = (float*)d_out;
    const int n = in_sizes[0] / EMB;   // 1,000,000 nodes

    int* start = (int*)d_ws;           // 4097 ints of scratch

    bounds_kernel<<<(NUM_GRAPHS + 1 + 255) / 256, 256, 0, stream>>>(batch, n, start);
    att_pool_kernel<<<NUM_GRAPHS, 256, 0, stream>>>(x, w, start, out);
}

// Round 2
// 647.246 us; speedup vs baseline: 1.0336x; 1.0336x over previous
//
#include <hip/hip_runtime.h>
#include <math.h>

#define NUM_GRAPHS 4096
#define EMB 128
#define NPW 128   // nodes per wave slab

// ws layout (floats): [wsum: G*128][denom: G][start: G+1 ints]
#define WSUM_OFF   0
#define DENOM_OFF  (NUM_GRAPHS * EMB)
#define START_OFF  (NUM_GRAPHS * EMB + NUM_GRAPHS)
#define ZERO_COUNT (NUM_GRAPHS * EMB + NUM_GRAPHS)

// Zero the accumulators and build start[] (start[g] = first i with batch[i] >= g)
// via boundary scatter: the unique thread i with batch[i-1] < g <= batch[i] writes start[g]=i.
__global__ __launch_bounds__(256) void init_kernel(const int* __restrict__ batch, int n,
                                                   float* __restrict__ ws) {
    const int i = blockIdx.x * 256 + threadIdx.x;
    if (i < ZERO_COUNT) ws[i] = 0.f;
    int* start = (int*)(ws + START_OFF);
    if (i < n) {
        const int b1 = batch[i];
        const int b0 = (i == 0) ? -1 : batch[i - 1];
        for (int g = b0 + 1; g <= b1; ++g) start[g] = i;
        if (i == n - 1)
            for (int g = b1 + 1; g <= NUM_GRAPHS; ++g) start[g] = n;
    }
}

// One wave per 128-node slab. 2 nodes per iteration, all in registers:
// lane = (half h -> node i+h) x (sub -> dims 4*sub..4*sub+3). Score via 5-shuffle
// half-reduce; e = exp(score) (no max shift: |score| <~ 17 << 88, fminf guard);
// acc += e*v. Flush to global atomics only at graph-run boundaries (~1.5 runs/slab).
__global__ __launch_bounds__(256) void pool_kernel(const float* __restrict__ x,
                                                   const float* __restrict__ w,
                                                   const int* __restrict__ batch,
                                                   float* __restrict__ ws, int n) {
    const int lane = threadIdx.x & 63;
    const int wid  = (blockIdx.x * 256 + threadIdx.x) >> 6;
    const int h    = lane >> 5;
    const int sub  = lane & 31;
    const int s0   = wid * NPW;
    if (s0 >= n) return;
    const int s1 = min(s0 + NPW, n);

    float* __restrict__ wsum  = ws + WSUM_OFF;
    float* __restrict__ denom = ws + DENOM_OFF;
    const int* __restrict__ start = (const int*)(ws + START_OFF);

    const float4 w4 = *(const float4*)(w + 4 * sub);

    int g = batch[s0];
    int i = s0;
    while (i < s1) {
        while (start[g + 1] <= i) ++g;            // wave-uniform, ~1 probe per run
        const int rend = min(s1, start[g + 1]);
        float4 acc = make_float4(0.f, 0.f, 0.f, 0.f);
        float lacc = 0.f;                          // sum of e (identical across half's lanes)

        #pragma unroll 4
        for (; i + 2 <= rend; i += 2) {
            const float4 v = *(const float4*)(x + (size_t)(i + h) * EMB + 4 * sub);
            float p = v.x * w4.x + v.y * w4.y + v.z * w4.z + v.w * w4.w;
            #pragma unroll
            for (int m = 16; m >= 1; m >>= 1) p += __shfl_xor(p, m, 64);
            const float e = __expf(fminf(p, 80.f));
            acc.x += e * v.x; acc.y += e * v.y; acc.z += e * v.z; acc.w += e * v.w;
            lacc += e;
        }
        if (i < rend) {                            // odd tail node (half 0 only)
            const int row = i + h;
            const int srow = min(row, n - 1);      // keep half-1's dead load in-bounds
            const float4 v = *(const float4*)(x + (size_t)srow * EMB + 4 * sub);
            float p = v.x * w4.x + v.y * w4.y + v.z * w4.z + v.w * w4.w;
            #pragma unroll
            for (int m = 16; m >= 1; m >>= 1) p += __shfl_xor(p, m, 64);
            const float e = (row < rend) ? __expf(fminf(p, 80.f)) : 0.f;
            acc.x += e * v.x; acc.y += e * v.y; acc.z += e * v.z; acc.w += e * v.w;
            lacc += e;
            i = rend;
        }

        // combine halves (same graph by construction), flush from half 0
        acc.x += __shfl_xor(acc.x, 32, 64);
        acc.y += __shfl_xor(acc.y, 32, 64);
        acc.z += __shfl_xor(acc.z, 32, 64);
        acc.w += __shfl_xor(acc.w, 32, 64);
        lacc  += __shfl_xor(lacc,  32, 64);
        if (h == 0) {
            float* dst = wsum + (size_t)g * EMB + 4 * sub;
            atomicAdd(dst + 0, acc.x);
            atomicAdd(dst + 1, acc.y);
            atomicAdd(dst + 2, acc.z);
            atomicAdd(dst + 3, acc.w);
            if (sub == 0) atomicAdd(denom + g, lacc);
        }
    }
}

__global__ __launch_bounds__(256) void finalize_kernel(const float* __restrict__ ws,
                                                       const float* __restrict__ w,
                                                       float* __restrict__ out) {
    const int tid = blockIdx.x * 256 + threadIdx.x;
    const float* wsum  = ws + WSUM_OFF;
    const float* denom = ws + DENOM_OFF;
    const int* start   = (const int*)(ws + START_OFF);
    if (tid < NUM_GRAPHS * EMB) {
        const int g = tid >> 7;
        const int cnt = start[g + 1] - start[g];
        const float d = fmaxf(denom[g], 1e-30f);
        out[tid] = wsum[tid] / (d * (float)max(cnt, 1));
    }
    if (tid < EMB) out[NUM_GRAPHS * EMB + tid] = w[tid];
}

extern "C" void kernel_launch(void* const* d_in, const int* in_sizes, int n_in,
                              void* d_out, int out_size, void* d_ws, size_t ws_size,
                              hipStream_t stream) {
    const float* x     = (const float*)d_in[0];
    const int*   batch = (const int*)d_in[1];
    const float* w     = (const float*)d_in[2];
    float* out = (float*)d_out;
    float* ws  = (float*)d_ws;
    const int n = in_sizes[0] / EMB;   // 1,000,000 nodes

    const int init_blocks = (n + 255) / 256;                 // covers ZERO_COUNT too
    init_kernel<<<init_blocks, 256, 0, stream>>>(batch, n, ws);

    const int waves = (n + NPW - 1) / NPW;
    const int pool_blocks = (waves + 3) / 4;                 // 4 waves per 256-thr block
    pool_kernel<<<pool_blocks, 256, 0, stream>>>(x, w, batch, ws, n);

    finalize_kernel<<<(NUM_GRAPHS * EMB + 255) / 256, 256, 0, stream>>>(ws, w, out);
}

// Round 3
// 634.202 us; speedup vs baseline: 1.0548x; 1.0206x over previous
//
#include <hip/hip_runtime.h>
#include <math.h>

#define NUM_GRAPHS 4096
#define EMB 128
#define NPW 128   // nodes per wave slab

typedef float v4f __attribute__((ext_vector_type(4)));

// ws layout (floats): [wsum: G*128][denom: G][start: G+1 ints]
#define WSUM_OFF   0
#define DENOM_OFF  (NUM_GRAPHS * EMB)
#define START_OFF  (NUM_GRAPHS * EMB + NUM_GRAPHS)
#define ZERO_COUNT (NUM_GRAPHS * EMB + NUM_GRAPHS)

// Zero accumulators and build start[] (start[g] = first i with batch[i] >= g)
// via boundary scatter.
__global__ __launch_bounds__(256) void init_kernel(const int* __restrict__ batch, int n,
                                                   float* __restrict__ ws) {
    const int i = blockIdx.x * 256 + threadIdx.x;
    if (i < ZERO_COUNT) ws[i] = 0.f;
    int* start = (int*)(ws + START_OFF);
    if (i < n) {
        const int b1 = batch[i];
        const int b0 = (i == 0) ? -1 : batch[i - 1];
        for (int g = b0 + 1; g <= b1; ++g) start[g] = i;
        if (i == n - 1)
            for (int g = b1 + 1; g <= NUM_GRAPHS; ++g) start[g] = n;
    }
}

// One wave per 128-node slab, 4 nodes per iteration (quarter-wave per node):
// lane = q*16 + s (q=node offset, s=dim group). Node i+q, dims [4s..4s+3] and
// [64+4s..64+4s+3]. Score reduce: masks 8,4,2,1 within each 16-lane quarter.
// No max-shift needed (|score| <~ 17 << 88; fminf guard). Flush to global
// atomics only at graph-run boundaries.
__global__ __launch_bounds__(256) void pool_kernel(const float* __restrict__ x,
                                                   const float* __restrict__ w,
                                                   const int* __restrict__ batch,
                                                   float* __restrict__ ws, int n) {
    const int lane = threadIdx.x & 63;
    const int wid  = (blockIdx.x * 256 + threadIdx.x) >> 6;
    const int q    = lane >> 4;    // node offset within 4-node group
    const int s    = lane & 15;    // dim group
    const int s0   = wid * NPW;
    if (s0 >= n) return;
    const int s1 = min(s0 + NPW, n);

    float* __restrict__ wsum  = ws + WSUM_OFF;
    float* __restrict__ denom = ws + DENOM_OFF;
    const int* __restrict__ start = (const int*)(ws + START_OFF);

    const v4f wa = *(const v4f*)(w + 4 * s);
    const v4f wb = *(const v4f*)(w + 64 + 4 * s);

    int g = batch[s0];
    int i = s0;
    while (i < s1) {
        while (start[g + 1] <= i) ++g;            // wave-uniform, ~1 probe per run
        const int rend = min(s1, start[g + 1]);
        v4f acc0 = (v4f)0.f, acc1 = (v4f)0.f;
        float lacc = 0.f;

        #pragma unroll 2
        for (; i + 4 <= rend; i += 4) {
            const float* xp = x + (size_t)(i + q) * EMB + 4 * s;
            const v4f v0 = __builtin_nontemporal_load((const v4f*)xp);
            const v4f v1 = __builtin_nontemporal_load((const v4f*)(xp + 64));
            float p = v0.x * wa.x + v0.y * wa.y + v0.z * wa.z + v0.w * wa.w
                    + v1.x * wb.x + v1.y * wb.y + v1.z * wb.z + v1.w * wb.w;
            #pragma unroll
            for (int m = 8; m >= 1; m >>= 1) p += __shfl_xor(p, m, 64);
            const float e = __expf(fminf(p, 80.f));
            acc0 += e * v0;
            acc1 += e * v1;
            lacc += e;
        }
        if (i < rend) {                            // 1..3 tail nodes
            const int row  = i + q;
            const int srow = min(row, n - 1);
            const float* xp = x + (size_t)srow * EMB + 4 * s;
            const v4f v0 = __builtin_nontemporal_load((const v4f*)xp);
            const v4f v1 = __builtin_nontemporal_load((const v4f*)(xp + 64));
            float p = v0.x * wa.x + v0.y * wa.y + v0.z * wa.z + v0.w * wa.w
                    + v1.x * wb.x + v1.y * wb.y + v1.z * wb.z + v1.w * wb.w;
            #pragma unroll
            for (int m = 8; m >= 1; m >>= 1) p += __shfl_xor(p, m, 64);
            const float e = (row < rend) ? __expf(fminf(p, 80.f)) : 0.f;
            acc0 += e * v0;
            acc1 += e * v1;
            lacc += e;
            i = rend;
        }

        // combine the 4 quarters (same graph by construction): xor 16, xor 32
        #pragma unroll
        for (int m = 16; m <= 32; m <<= 1) {
            acc0.x += __shfl_xor(acc0.x, m, 64);
            acc0.y += __shfl_xor(acc0.y, m, 64);
            acc0.z += __shfl_xor(acc0.z, m, 64);
            acc0.w += __shfl_xor(acc0.w, m, 64);
            acc1.x += __shfl_xor(acc1.x, m, 64);
            acc1.y += __shfl_xor(acc1.y, m, 64);
            acc1.z += __shfl_xor(acc1.z, m, 64);
            acc1.w += __shfl_xor(acc1.w, m, 64);
            lacc   += __shfl_xor(lacc,   m, 64);
        }
        if (q == 0) {                              // lanes 0..15 flush
            float* d0 = wsum + (size_t)g * EMB + 4 * s;
            atomicAdd(d0 + 0,  acc0.x);
            atomicAdd(d0 + 1,  acc0.y);
            atomicAdd(d0 + 2,  acc0.z);
            atomicAdd(d0 + 3,  acc0.w);
            atomicAdd(d0 + 64, acc1.x);
            atomicAdd(d0 + 65, acc1.y);
            atomicAdd(d0 + 66, acc1.z);
            atomicAdd(d0 + 67, acc1.w);
            if (s == 0) atomicAdd(denom + g, lacc);
        }
    }
}

__global__ __launch_bounds__(256) void finalize_kernel(const float* __restrict__ ws,
                                                       const float* __restrict__ w,
                                                       float* __restrict__ out) {
    const int tid = blockIdx.x * 256 + threadIdx.x;
    const float* wsum  = ws + WSUM_OFF;
    const float* denom = ws + DENOM_OFF;
    const int* start   = (const int*)(ws + START_OFF);
    if (tid < NUM_GRAPHS * EMB) {
        const int g = tid >> 7;
        const int cnt = start[g + 1] - start[g];
        const float d = fmaxf(denom[g], 1e-30f);
        out[tid] = wsum[tid] / (d * (float)max(cnt, 1));
    }
    if (tid < EMB) out[NUM_GRAPHS * EMB + tid] = w[tid];
}

extern "C" void kernel_launch(void* const* d_in, const int* in_sizes, int n_in,
                              void* d_out, int out_size, void* d_ws, size_t ws_size,
                              hipStream_t stream) {
    const float* x     = (const float*)d_in[0];
    const int*   batch = (const int*)d_in[1];
    const float* w     = (const float*)d_in[2];
    float* out = (float*)d_out;
    float* ws  = (float*)d_ws;
    const int n = in_sizes[0] / EMB;   // 1,000,000 nodes

    const int init_blocks = (n + 255) / 256;                 // covers ZERO_COUNT too
    init_kernel<<<init_blocks, 256, 0, stream>>>(batch, n, ws);

    const int waves = (n + NPW - 1) / NPW;
    const int pool_blocks = (waves + 3) / 4;                 // 4 waves / 256-thr block
    pool_kernel<<<pool_blocks, 256, 0, stream>>>(x, w, batch, ws, n);

    finalize_kernel<<<(NUM_GRAPHS * EMB + 255) / 256, 256, 0, stream>>>(ws, w, out);
}

// Round 4
// 629.800 us; speedup vs baseline: 1.0622x; 1.0070x over previous
//
#include <hip/hip_runtime.h>
#include <math.h>

#define NUM_GRAPHS 4096
#define EMB 128
#define NWAVES 4096     // 1024 blocks x 4 waves: 4 blocks/CU, statically balanced

typedef float v4f __attribute__((ext_vector_type(4)));

// ws layout (floats): [wsum: G*128][denom: G][start: G+1 ints]
#define WSUM_OFF   0
#define DENOM_OFF  (NUM_GRAPHS * EMB)
#define START_OFF  (NUM_GRAPHS * EMB + NUM_GRAPHS)
#define ZERO_COUNT (NUM_GRAPHS * EMB + NUM_GRAPHS)

// Zero accumulators and build start[] (start[g] = first i with batch[i] >= g)
// via boundary scatter.
__global__ __launch_bounds__(256) void init_kernel(const int* __restrict__ batch, int n,
                                                   float* __restrict__ ws) {
    const int i = blockIdx.x * 256 + threadIdx.x;
    if (i < ZERO_COUNT) ws[i] = 0.f;
    int* start = (int*)(ws + START_OFF);
    if (i < n) {
        const int b1 = batch[i];
        const int b0 = (i == 0) ? -1 : batch[i - 1];
        for (int g = b0 + 1; g <= b1; ++g) start[g] = i;
        if (i == n - 1)
            for (int g = b1 + 1; g <= NUM_GRAPHS; ++g) start[g] = n;
    }
}

// Statically balanced: wave wid owns nodes [wid*n/W, (wid+1)*n/W) — equal bytes
// per wave, 4 identical blocks per CU -> no dispatch tail. 4 nodes/iteration
// (quarter-wave per node): lane = q*16+s; node i+q, dims [4s..4s+3] and
// [64+4s..]. Score reduce intra-16 (masks 8,4,2,1). No max-shift needed
// (|score| <~ 17 << 88; fminf guard). Atomic flush only at graph-run ends.
__global__ __launch_bounds__(256) void pool_kernel(const float* __restrict__ x,
                                                   const float* __restrict__ w,
                                                   const int* __restrict__ batch,
                                                   float* __restrict__ ws, int n) {
    const int lane = threadIdx.x & 63;
    const int wid  = (blockIdx.x * 256 + threadIdx.x) >> 6;
    const int q    = lane >> 4;    // node offset within 4-node group
    const int s    = lane & 15;    // dim group
    const int s0 = (int)((long long)wid * n / NWAVES);
    const int s1 = (int)((long long)(wid + 1) * n / NWAVES);
    if (s0 >= s1) return;

    float* __restrict__ wsum  = ws + WSUM_OFF;
    float* __restrict__ denom = ws + DENOM_OFF;
    const int* __restrict__ start = (const int*)(ws + START_OFF);

    const v4f wa = *(const v4f*)(w + 4 * s);
    const v4f wb = *(const v4f*)(w + 64 + 4 * s);

    int g = batch[s0];
    int i = s0;
    while (i < s1) {
        while (start[g + 1] <= i) ++g;            // wave-uniform, ~1 probe per run
        const int rend = min(s1, start[g + 1]);
        v4f acc0 = (v4f)0.f, acc1 = (v4f)0.f;
        float lacc = 0.f;

        #pragma unroll 4
        for (; i + 4 <= rend; i += 4) {
            const float* xp = x + (size_t)(i + q) * EMB + 4 * s;
            const v4f v0 = __builtin_nontemporal_load((const v4f*)xp);
            const v4f v1 = __builtin_nontemporal_load((const v4f*)(xp + 64));
            float p = v0.x * wa.x + v0.y * wa.y + v0.z * wa.z + v0.w * wa.w
                    + v1.x * wb.x + v1.y * wb.y + v1.z * wb.z + v1.w * wb.w;
            #pragma unroll
            for (int m = 8; m >= 1; m >>= 1) p += __shfl_xor(p, m, 64);
            const float e = __expf(fminf(p, 80.f));
            acc0 += e * v0;
            acc1 += e * v1;
            lacc += e;
        }
        if (i < rend) {                            // 1..3 tail nodes of this run
            const int row  = i + q;
            const int srow = min(row, n - 1);
            const float* xp = x + (size_t)srow * EMB + 4 * s;
            const v4f v0 = __builtin_nontemporal_load((const v4f*)xp);
            const v4f v1 = __builtin_nontemporal_load((const v4f*)(xp + 64));
            float p = v0.x * wa.x + v0.y * wa.y + v0.z * wa.z + v0.w * wa.w
                    + v1.x * wb.x + v1.y * wb.y + v1.z * wb.z + v1.w * wb.w;
            #pragma unroll
            for (int m = 8; m >= 1; m >>= 1) p += __shfl_xor(p, m, 64);
            const float e = (row < rend) ? __expf(fminf(p, 80.f)) : 0.f;
            acc0 += e * v0;
            acc1 += e * v1;
            lacc += e;
            i = rend;
        }

        // combine the 4 quarters (same graph by construction): xor 16, xor 32
        #pragma unroll
        for (int m = 16; m <= 32; m <<= 1) {
            acc0.x += __shfl_xor(acc0.x, m, 64);
            acc0.y += __shfl_xor(acc0.y, m, 64);
            acc0.z += __shfl_xor(acc0.z, m, 64);
            acc0.w += __shfl_xor(acc0.w, m, 64);
            acc1.x += __shfl_xor(acc1.x, m, 64);
            acc1.y += __shfl_xor(acc1.y, m, 64);
            acc1.z += __shfl_xor(acc1.z, m, 64);
            acc1.w += __shfl_xor(acc1.w, m, 64);
            lacc   += __shfl_xor(lacc,   m, 64);
        }
        if (q == 0) {                              // lanes 0..15 flush
            float* d0 = wsum + (size_t)g * EMB + 4 * s;
            atomicAdd(d0 + 0,  acc0.x);
            atomicAdd(d0 + 1,  acc0.y);
            atomicAdd(d0 + 2,  acc0.z);
            atomicAdd(d0 + 3,  acc0.w);
            atomicAdd(d0 + 64, acc1.x);
            atomicAdd(d0 + 65, acc1.y);
            atomicAdd(d0 + 66, acc1.z);
            atomicAdd(d0 + 67, acc1.w);
            if (s == 0) atomicAdd(denom + g, lacc);
        }
    }
}

__global__ __launch_bounds__(256) void finalize_kernel(const float* __restrict__ ws,
                                                       const float* __restrict__ w,
                                                       float* __restrict__ out) {
    const int tid = blockIdx.x * 256 + threadIdx.x;
    const float* wsum  = ws + WSUM_OFF;
    const float* denom = ws + DENOM_OFF;
    const int* start   = (const int*)(ws + START_OFF);
    if (tid < NUM_GRAPHS * EMB) {
        const int g = tid >> 7;
        const int cnt = start[g + 1] - start[g];
        const float d = fmaxf(denom[g], 1e-30f);
        out[tid] = wsum[tid] / (d * (float)max(cnt, 1));
    }
    if (tid < EMB) out[NUM_GRAPHS * EMB + tid] = w[tid];
}

extern "C" void kernel_launch(void* const* d_in, const int* in_sizes, int n_in,
                              void* d_out, int out_size, void* d_ws, size_t ws_size,
                              hipStream_t stream) {
    const float* x     = (const float*)d_in[0];
    const int*   batch = (const int*)d_in[1];
    const float* w     = (const float*)d_in[2];
    float* out = (float*)d_out;
    float* ws  = (float*)d_ws;
    const int n = in_sizes[0] / EMB;   // 1,000,000 nodes

    const int init_blocks = (n + 255) / 256;                 // covers ZERO_COUNT too
    init_kernel<<<init_blocks, 256, 0, stream>>>(batch, n, ws);

    pool_kernel<<<NWAVES / 4, 256, 0, stream>>>(x, w, batch, ws, n);

    finalize_kernel<<<(NUM_GRAPHS * EMB + 255) / 256, 256, 0, stream>>>(ws, w, out);
}